// Round 8
// baseline (208.446 us; speedup 1.0000x reference)
//
#include <hip/hip_runtime.h>
#include <hip/hip_bf16.h>

// Reduction of the reference (h0 = 0):
//   z  = sigmoid(x @ Wz + bz),  t = tanh(x @ Wh + bh),  h = (1-z)*t
//   out= sigmoid(relu(h @ fc1) @ fc2)       (w_r/b_r, edge_index dead)
// Main cost: [100000,256] @ [256,64] -> bf16 MFMA, memory-bound on x.
//
// R4-R7 post-mortem: all ~63-67 us, every pipe <12%; R6's L3-resident
// replay also 63 us -> concurrency-bound, not byte-source-bound. Root
// cause: 100k nodes / 32-node wave-tiles = only 12.2 waves/CU of total
// work (measured ~8 resident). R8: SPLIT K. Block = 4 waves = 2 node-tiles
// x 2 K-halves -> 24.4 waves/CU of work, half-length load chains per wave,
// 1563 blocks. K-halves combine through LDS in the epilogue only (3
// barriers, none in the K-loop). A-loads nontemporal (streamed once).

#define NF    256
#define TILE  32            // nodes per wave-tile
#define NPB   64            // nodes per block (2 tiles)
#define NTHR  256           // 4 waves: wave = tile + 2*khalf
#define CSTR  68            // LDS combine/h row stride (floats); 272B = 16*17
#define HKT   8             // kt steps per K-half

typedef __attribute__((ext_vector_type(8)))  short  short8;
typedef __attribute__((ext_vector_type(16))) float  floatx16;
typedef __attribute__((ext_vector_type(4)))  float  f32x4;

__device__ __forceinline__ unsigned f2bf(float f) {
    __hip_bfloat16 h = __float2bfloat16(f);   // RNE
    return (unsigned)*(unsigned short*)&h;
}
__device__ __forceinline__ float fast_sigmoid(float v) {
    return 1.0f / (1.0f + __expf(-v));
}
__device__ __forceinline__ float fast_tanh(float v) {
    return 1.0f - 2.0f / (1.0f + __expf(2.0f * v));
}

// ---- prep: fold w[0]+w[1], emit bf16 in 32x32x16 B-fragment order:
// Wf[((kt*2+nt)*64 + lane)*8 + j] = W[kt*16 + (lane>>5)*8 + j][nt*32 + (lane&31)]
__global__ void prep_W(const float* __restrict__ wz,   // (2, 288, 32)
                       const float* __restrict__ wh,   // (2, 288, 32)
                       unsigned short* __restrict__ Wf) // 16*2*64*8 bf16
{
    int idx = blockIdx.x * blockDim.x + threadIdx.x;   // 0 .. 16383
    if (idx >= NF * 64) return;
    int j    = idx & 7;
    int lane = (idx >> 3) & 63;
    int nt   = (idx >> 9) & 1;
    int kt   = idx >> 10;                  // 0..15
    int k = kt * 16 + (lane >> 5) * 8 + j; // 0..255
    int o = nt * 32 + (lane & 31);         // 0..63
    const int PLANE = 288 * 32;
    float v;
    if (o < 32) v = wz[k * 32 + o]        + wz[PLANE + k * 32 + o];
    else        v = wh[k * 32 + (o - 32)] + wh[PLANE + k * 32 + (o - 32)];
    Wf[idx] = (unsigned short)f2bf(v);
}

__global__ void __launch_bounds__(NTHR, 5)
rgcn_main(const float* __restrict__ x,     // [N, 256]
          const unsigned short* __restrict__ Wf, // B-frags (ws)
          const float* __restrict__ bz,    // [32]
          const float* __restrict__ bh,    // [32]
          const float* __restrict__ fc1w,  // [32][32] (in,out)
          const float* __restrict__ fc1b,  // [32]
          const float* __restrict__ fc2w,  // [32]
          const float* __restrict__ fc2b,  // [1]
          float* __restrict__ out,         // [N]
          int n_nodes)
{
    __shared__ __align__(16) float Xc[NPB * CSTR];   // 17408 B

    const int tid   = threadIdx.x;
    const int lane  = tid & 63;
    const int wave  = tid >> 6;            // 0..3
    const int tile  = wave & 1;            // node sub-tile
    const int khalf = wave >> 1;           // K-half 0|1
    const int node0 = blockIdx.x * NPB;

    // A source: lane's node row, this wave's K-half
    const int nc = lane & 31;              // also output col later
    int gn = node0 + tile * TILE + nc;
    if (gn >= n_nodes) gn = n_nodes - 1;   // junk but finite; never stored
    const float* xr = x + (size_t)gn * NF + khalf * 128 + (lane >> 5) * 8;

    floatx16 acc0 = {};                    // cols 0..31  (z)
    floatx16 acc1 = {};                    // cols 32..63 (h~)

#pragma unroll
    for (int kt = 0; kt < HKT; ++kt) {
        // A: nontemporal streamed fp32 (keeps L1 for B/fc weights)
        f32x4 v0 = __builtin_nontemporal_load((const f32x4*)(xr + kt * 16));
        f32x4 v1 = __builtin_nontemporal_load((const f32x4*)(xr + kt * 16 + 4));
        // B: pre-swizzled fragments, 32 KB -> L2/L1-hot
        int g = khalf * HKT + kt;
        uint4 b0u = ((const uint4*)Wf)[(size_t)(g * 2 + 0) * 64 + lane];
        uint4 b1u = ((const uint4*)Wf)[(size_t)(g * 2 + 1) * 64 + lane];
        union { short8 s; unsigned u[4]; } a, b0, b1;
        a.u[0] = f2bf(v0.x) | (f2bf(v0.y) << 16);
        a.u[1] = f2bf(v0.z) | (f2bf(v0.w) << 16);
        a.u[2] = f2bf(v1.x) | (f2bf(v1.y) << 16);
        a.u[3] = f2bf(v1.z) | (f2bf(v1.w) << 16);
        b0.u[0] = b0u.x; b0.u[1] = b0u.y; b0.u[2] = b0u.z; b0.u[3] = b0u.w;
        b1.u[0] = b1u.x; b1.u[1] = b1u.y; b1.u[2] = b1u.z; b1.u[3] = b1u.w;
        acc0 = __builtin_amdgcn_mfma_f32_32x32x16_bf16(a.s, b0.s, acc0, 0, 0, 0);
        acc1 = __builtin_amdgcn_mfma_f32_32x32x16_bf16(a.s, b1.s, acc1, 0, 0, 0);
    }

    // ---- combine K-halves through LDS, then gates + fc head.
    // C/D layout: col=lane&31, row=(r&3)+8*(r>>2)+4*(lane>>5).
    if (khalf == 1) {
#pragma unroll
        for (int r = 0; r < 16; ++r) {
            int row = (r & 3) + 8 * (r >> 2) + 4 * (lane >> 5);
            int base = (tile * TILE + row) * CSTR;
            Xc[base + nc]      = acc0[r];
            Xc[base + 32 + nc] = acc1[r];
        }
    }
    __syncthreads();

    if (khalf == 0) {
        const float bzn = bz[nc];
        const float bhn = bh[nc];
#pragma unroll
        for (int r = 0; r < 16; ++r) {
            int row = (r & 3) + 8 * (r >> 2) + 4 * (lane >> 5);
            int base = (tile * TILE + row) * CSTR;
            float s0 = acc0[r] + Xc[base + nc];
            float s1 = acc1[r] + Xc[base + 32 + nc];
            float z = fast_sigmoid(s0 + bzn);
            float t = fast_tanh   (s1 + bhn);
            acc0[r] = (1.0f - z) * t;        // stash h, write after barrier
        }
    }
    __syncthreads();                         // all reads of acc-dump done
    if (khalf == 0) {
#pragma unroll
        for (int r = 0; r < 16; ++r) {
            int row = (r & 3) + 8 * (r >> 2) + 4 * (lane >> 5);
            Xc[(tile * TILE + row) * CSTR + nc] = acc0[r];
        }
    }
    __syncthreads();

    // fc head on waves 0,1: 2 lanes per node (j-halves), 32 nodes per wave
    if (khalf == 0) {
        const int nl   = nc;                 // node within tile
        const int half = lane >> 5;          // fc1 j-range half
        const float* hp = Xc + (tile * TILE + nl) * CSTR;
        float h[32];
#pragma unroll
        for (int q = 0; q < 8; ++q) {
            float4 v = *(const float4*)(hp + q * 4);
            h[q * 4 + 0] = v.x; h[q * 4 + 1] = v.y;
            h[q * 4 + 2] = v.z; h[q * 4 + 3] = v.w;
        }
        float part = 0.0f;
        for (int jj = 0; jj < 16; ++jj) {
            int j = (half << 4) + jj;
            float s = fc1b[j];
#pragma unroll
            for (int o = 0; o < 32; ++o)
                s = fmaf(h[o], fc1w[o * 32 + j], s);
            part = fmaf(fmaxf(s, 0.0f), fc2w[j], part);
        }
        part += __shfl_xor(part, 32);        // combine j-halves
        if (half == 0) {
            int g = node0 + tile * TILE + nl;
            if (g < n_nodes)
                out[g] = fast_sigmoid(part + fc2b[0]);
        }
    }
}

extern "C" void kernel_launch(void* const* d_in, const int* in_sizes, int n_in,
                              void* d_out, int out_size, void* d_ws, size_t ws_size,
                              hipStream_t stream) {
    // 0:x 1:edge_index(dead) 2:w_z 3:b_z 4:w_r(dead) 5:b_r(dead)
    // 6:w_h 7:b_h 8:fc1_w 9:fc1_b 10:fc2_w 11:fc2_b
    const float* x    = (const float*)d_in[0];
    const float* wz   = (const float*)d_in[2];
    const float* bz   = (const float*)d_in[3];
    const float* wh   = (const float*)d_in[6];
    const float* bh   = (const float*)d_in[7];
    const float* fc1w = (const float*)d_in[8];
    const float* fc1b = (const float*)d_in[9];
    const float* fc2w = (const float*)d_in[10];
    const float* fc2b = (const float*)d_in[11];
    float* out = (float*)d_out;
    unsigned short* Wf = (unsigned short*)d_ws;   // 32 KB of B-fragments

    const int n = in_sizes[0] / NF;   // 100000

    prep_W<<<(NF * 64 + 255) / 256, 256, 0, stream>>>(wz, wh, Wf);
    rgcn_main<<<(n + NPB - 1) / NPB, NTHR, 0, stream>>>(
        x, Wf, bz, bh, fc1w, fc1b, fc2w, fc2b, out, n);
}

// Round 9
// 206.488 us; speedup vs baseline: 1.0095x; 1.0095x over previous
//
#include <hip/hip_runtime.h>
#include <hip/hip_bf16.h>

// Reduction of the reference (h0 = 0):
//   z  = sigmoid(x @ Wz + bz),  t = tanh(x @ Wh + bh),  h = (1-z)*t
//   out= sigmoid(relu(h @ fc1) @ fc2)       (w_r/b_r, edge_index dead)
// Main cost: [100000,256] @ [256,64] -> bf16 MFMA.
//
// R8 post-mortem: 2-way K-split pushed rgcn_main below the harness's own
// 59-us d_ws-poison fill (fell out of rocprof top-5). The binding model is
// per-wave serial load chains / resident-wave overlap, not byte throughput
// (R6's L3-resident replay was equally slow; the 6.9 TB/s fills prove the
// memory system streams). R9: 4-way K-split -- block = 4 waves = 1 node
// tile x 4 K-quarters, 3125 blocks (no tail), 48.8 waves/CU of work,
// ~20 resident; per-wave chain halves again (4 kt). Partials combined in
// LDS with a single barrier; wave 0 does gates + fc head.

#define NF    256
#define TILE  32            // nodes per block (one tile)
#define NTHR  256           // 4 waves = 4 K-quarters
#define QKT   4             // kt steps per K-quarter
#define CSTR  68            // partial/h row stride (floats); 272 B, 16B-mult

typedef __attribute__((ext_vector_type(8)))  short  short8;
typedef __attribute__((ext_vector_type(16))) float  floatx16;
typedef __attribute__((ext_vector_type(4)))  float  f32x4;

__device__ __forceinline__ unsigned f2bf(float f) {
    __hip_bfloat16 h = __float2bfloat16(f);   // RNE
    return (unsigned)*(unsigned short*)&h;
}
__device__ __forceinline__ float fast_sigmoid(float v) {
    return 1.0f / (1.0f + __expf(-v));
}
__device__ __forceinline__ float fast_tanh(float v) {
    return 1.0f - 2.0f / (1.0f + __expf(2.0f * v));
}

// ---- prep: fold w[0]+w[1], emit bf16 in 32x32x16 B-fragment order:
// Wf[((kt*2+nt)*64 + lane)*8 + j] = W[kt*16 + (lane>>5)*8 + j][nt*32 + (lane&31)]
__global__ void prep_W(const float* __restrict__ wz,   // (2, 288, 32)
                       const float* __restrict__ wh,   // (2, 288, 32)
                       unsigned short* __restrict__ Wf) // 16*2*64*8 bf16
{
    int idx = blockIdx.x * blockDim.x + threadIdx.x;   // 0 .. 16383
    if (idx >= NF * 64) return;
    int j    = idx & 7;
    int lane = (idx >> 3) & 63;
    int nt   = (idx >> 9) & 1;
    int kt   = idx >> 10;                  // 0..15
    int k = kt * 16 + (lane >> 5) * 8 + j; // 0..255
    int o = nt * 32 + (lane & 31);         // 0..63
    const int PLANE = 288 * 32;
    float v;
    if (o < 32) v = wz[k * 32 + o]        + wz[PLANE + k * 32 + o];
    else        v = wh[k * 32 + (o - 32)] + wh[PLANE + k * 32 + (o - 32)];
    Wf[idx] = (unsigned short)f2bf(v);
}

__global__ void __launch_bounds__(NTHR, 5)
rgcn_main(const float* __restrict__ x,     // [N, 256]
          const unsigned short* __restrict__ Wf, // B-frags (ws)
          const float* __restrict__ bz,    // [32]
          const float* __restrict__ bh,    // [32]
          const float* __restrict__ fc1w,  // [32][32] (in,out)
          const float* __restrict__ fc1b,  // [32]
          const float* __restrict__ fc2w,  // [32]
          const float* __restrict__ fc2b,  // [1]
          float* __restrict__ out,         // [N]
          int n_nodes)
{
    __shared__ __align__(16) float Pc[3 * TILE * CSTR];   // 26112 B

    const int tid   = threadIdx.x;
    const int lane  = tid & 63;
    const int q     = tid >> 6;            // K-quarter 0..3
    const int node0 = blockIdx.x * TILE;

    // A source: lane's node row, this wave's K-quarter
    const int nc = lane & 31;              // node (and later: output col)
    int gn = node0 + nc;
    if (gn >= n_nodes) gn = n_nodes - 1;   // junk but finite; never stored
    const float* xr = x + (size_t)gn * NF + q * 64 + (lane >> 5) * 8;

    floatx16 acc0 = {};                    // cols 0..31  (z)
    floatx16 acc1 = {};                    // cols 32..63 (h~)

#pragma unroll
    for (int kt = 0; kt < QKT; ++kt) {
        // A: nontemporal streamed fp32 (x is read exactly once)
        f32x4 v0 = __builtin_nontemporal_load((const f32x4*)(xr + kt * 16));
        f32x4 v1 = __builtin_nontemporal_load((const f32x4*)(xr + kt * 16 + 4));
        // B: pre-swizzled fragments, 32 KB -> L2/L1-hot
        int g = q * QKT + kt;
        uint4 b0u = ((const uint4*)Wf)[(size_t)(g * 2 + 0) * 64 + lane];
        uint4 b1u = ((const uint4*)Wf)[(size_t)(g * 2 + 1) * 64 + lane];
        union { short8 s; unsigned u[4]; } a, b0, b1;
        a.u[0] = f2bf(v0.x) | (f2bf(v0.y) << 16);
        a.u[1] = f2bf(v0.z) | (f2bf(v0.w) << 16);
        a.u[2] = f2bf(v1.x) | (f2bf(v1.y) << 16);
        a.u[3] = f2bf(v1.z) | (f2bf(v1.w) << 16);
        b0.u[0] = b0u.x; b0.u[1] = b0u.y; b0.u[2] = b0u.z; b0.u[3] = b0u.w;
        b1.u[0] = b1u.x; b1.u[1] = b1u.y; b1.u[2] = b1u.z; b1.u[3] = b1u.w;
        acc0 = __builtin_amdgcn_mfma_f32_32x32x16_bf16(a.s, b0.s, acc0, 0, 0, 0);
        acc1 = __builtin_amdgcn_mfma_f32_32x32x16_bf16(a.s, b1.s, acc1, 0, 0, 0);
    }

    // ---- combine the 4 K-quarters. C/D layout: col=lane&31,
    // row=(r&3)+8*(r>>2)+4*(lane>>5). Waves 1..3 dump; wave 0 reduces.
    if (q > 0) {
        float* P = Pc + (q - 1) * TILE * CSTR;
#pragma unroll
        for (int r = 0; r < 16; ++r) {
            int row = (r & 3) + 8 * (r >> 2) + 4 * (lane >> 5);
            P[row * CSTR + nc]      = acc0[r];   // 32 lanes, consec cols
            P[row * CSTR + 32 + nc] = acc1[r];   // -> conflict-free
        }
    }
    __syncthreads();                       // the only block-wide barrier

    if (q == 0) {
        const float bzn = bz[nc];
        const float bhn = bh[nc];
        float* P0 = Pc;
        float* P1 = Pc + TILE * CSTR;
        float* P2 = Pc + 2 * TILE * CSTR;
#pragma unroll
        for (int r = 0; r < 16; ++r) {
            int row  = (r & 3) + 8 * (r >> 2) + 4 * (lane >> 5);
            int base = row * CSTR;
            float s0 = acc0[r] + P0[base + nc] + P1[base + nc] + P2[base + nc];
            float s1 = acc1[r] + P0[base + 32 + nc] + P1[base + 32 + nc]
                               + P2[base + 32 + nc];
            float z = fast_sigmoid(s0 + bzn);
            float t = fast_tanh   (s1 + bhn);
            acc0[r] = (1.0f - z) * t;      // h, still in C/D layout
        }
        // h -> LDS (reuse P0; reads above already consumed, same-wave order)
#pragma unroll
        for (int r = 0; r < 16; ++r) {
            int row = (r & 3) + 8 * (r >> 2) + 4 * (lane >> 5);
            P0[row * CSTR + nc] = acc0[r];
        }
        asm volatile("s_waitcnt lgkmcnt(0)" ::: "memory");  // wave-private

        // fc head: 2 lanes per node (j-halves), 32 nodes in this wave
        const int nl   = nc;
        const int half = lane >> 5;
        const float* hp = P0 + nl * CSTR;
        float h[32];
#pragma unroll
        for (int m = 0; m < 8; ++m) {
            float4 v = *(const float4*)(hp + m * 4);
            h[m * 4 + 0] = v.x; h[m * 4 + 1] = v.y;
            h[m * 4 + 2] = v.z; h[m * 4 + 3] = v.w;
        }
        float part = 0.0f;
        for (int jj = 0; jj < 16; ++jj) {
            int j = (half << 4) + jj;
            float s = fc1b[j];
#pragma unroll
            for (int o = 0; o < 32; ++o)
                s = fmaf(h[o], fc1w[o * 32 + j], s);
            part = fmaf(fmaxf(s, 0.0f), fc2w[j], part);
        }
        part += __shfl_xor(part, 32);      // combine j-halves
        if (half == 0) {
            int g = node0 + nl;
            if (g < n_nodes)
                out[g] = fast_sigmoid(part + fc2b[0]);   // coalesced
        }
    }
}

extern "C" void kernel_launch(void* const* d_in, const int* in_sizes, int n_in,
                              void* d_out, int out_size, void* d_ws, size_t ws_size,
                              hipStream_t stream) {
    // 0:x 1:edge_index(dead) 2:w_z 3:b_z 4:w_r(dead) 5:b_r(dead)
    // 6:w_h 7:b_h 8:fc1_w 9:fc1_b 10:fc2_w 11:fc2_b
    const float* x    = (const float*)d_in[0];
    const float* wz   = (const float*)d_in[2];
    const float* bz   = (const float*)d_in[3];
    const float* wh   = (const float*)d_in[6];
    const float* bh   = (const float*)d_in[7];
    const float* fc1w = (const float*)d_in[8];
    const float* fc1b = (const float*)d_in[9];
    const float* fc2w = (const float*)d_in[10];
    const float* fc2b = (const float*)d_in[11];
    float* out = (float*)d_out;
    unsigned short* Wf = (unsigned short*)d_ws;   // 32 KB of B-fragments

    const int n = in_sizes[0] / NF;   // 100000

    prep_W<<<(NF * 64 + 255) / 256, 256, 0, stream>>>(wz, wh, Wf);
    rgcn_main<<<(n + TILE - 1) / TILE, NTHR, 0, stream>>>(
        x, Wf, bz, bh, fc1w, fc1b, fc2w, fc2b, out, n);
}